// Round 7
// baseline (422.324 us; speedup 1.0000x reference)
//
#include <hip/hip_runtime.h>
#include <math.h>

#define NIMG 116          // 4*29 images
#define TW 118            // output tile width  (phase-1 columns = TW+10 = 128)
#define TH 16             // output tile height (strips of 8 rows, 2 strips)

// 11-tap Gaussian (size=11, sigma=1.5), fp32 values matching the reference.
static constexpr float W[11] = {
    0.00102838f, 0.00759876f, 0.03600078f, 0.10936075f, 0.21300554f,
    0.26601172f, 0.21300554f, 0.10936075f, 0.03600078f, 0.00759876f,
    0.00102838f};

typedef float f2 __attribute__((ext_vector_type(2)));

__device__ __forceinline__ f2 pkfma(f2 a, f2 b, f2 c) {
#if __has_builtin(__builtin_elementwise_fma)
    return __builtin_elementwise_fma(a, b, c);
#else
    f2 r; r.x = fmaf(a.x, b.x, c.x); r.y = fmaf(a.y, b.y, c.y); return r;
#endif
}

__device__ __forceinline__ float frcp(float x) {
    return __builtin_amdgcn_rcpf(x);
}

__device__ __forceinline__ float fsig(float x) {
    float e = __builtin_amdgcn_exp2f(x * -1.4426950408889634f);
    return frcp(1.0f + e);
}

// ---------------------------------------------------------------------------
// Per-tile SSIM body, packed-FP32 + bank-swizzled LDS + staged loads.
// R5: pkfma cut VALU issue 80->58% but f2-interleaved LDS raised conflicts
//     8M->20M — net zero.
// R6: float4-column {mu1,mu2,xx,xy} plane + XOR swizzle -> conflicts 0,
//     L0 193->181 µs.
// R7: phase-1 load restructure. OLD: 36 strided dword loads/thread (column
//     of 18 rows, 256 B/wave coalescing, strips re-read 10-row overlap =
//     36 rows issued vs 26 unique). NEW (interior blocks): block stages the
//     unique 26x128x2 region row-major into LDS via 13 coalesced f2 loads
//     per thread (512 B/wave), then reads columns from LDS (row-major write
//     = conflict-free; column read = 4 B lane stride = 2-way = free). Raw
//     buffer (6656 floats) aliases the plane region; barriers order reuse.
//     Border blocks (row/col clamping; ALL blocks at N<=64) keep the old
//     direct clamped path. Downstream math identical -> bit-identical result.
// LDS: planes 8192 f + yy 2048 f = 40960 B -> exactly 4 blocks/CU
// (R4: 32 KB/5 blocks raised HBM traffic 12%; locality beats occupancy).
// History: R1 keep-alive asm -5 µs reverted; R2 grid.sync raced; R4 tail
// serialization +35 µs reverted. Launch structure = proven 5 + finalize.
// ---------------------------------------------------------------------------
template <int N, int M, bool SIG, bool POOL, bool SKIPYY, bool NARROW>
__device__ __forceinline__ void ssim_tile(
    const float* __restrict__ X, const float* __restrict__ Y,
    float* __restrict__ accSsim, float* __restrict__ accCs,
    float* __restrict__ poolX, float* __restrict__ poolY,
    int img, int bx, int by, float* smem) {
    const int tid = threadIdx.x;
    const int ox0 = NARROW ? 0 : bx * TW;
    const int oy0 = by * TH;
    const long base = (long)img * N * N;

    // ================= phase 1: load ========================================
    const int c  = tid & 127;      // tile-local column 0..127
    const int s  = tid >> 7;       // strip 0/1 (rows 8s .. 8s+7 of v)
    const int ci = ox0 + c;        // global column
    constexpr int half = N >> 1;
    const int powned = NARROW ? N : min(TW, N - ox0);  // pool column ownership

    const float* __restrict__ Xb = X + base;
    const float* __restrict__ Yb = Y + base;

    // interior: no row/col clamping anywhere in this block (block-uniform)
    const bool interior = (oy0 + 25 < N) && (ox0 + 127 < N);

    f2 xy[18];                     // .x = X row value, .y = Y row value
    if (interior) {
        // ---- phase 0: coalesced staging of the unique 26x128x2 region -----
        // raw layout in smem floats: x-plane [0,3328) = [26][128],
        //                            y-plane [3328,6656)
        const long rowbase = (long)oy0 * N + ox0;
        f2 stg[13];
#pragma unroll
        for (int it = 0; it < 13; it++) {
            int idx2 = tid + 256 * it;          // 0..3327 (f2 index)
            int img2 = idx2 >= 1664;            // 0: X, 1: Y
            int rem = idx2 - img2 * 1664;
            int rr = rem >> 6;                  // row 0..25 (64 f2 per row)
            int cc2 = (rem & 63) * 2;           // col 0..126, even -> 8B align
            const float* src = (img2 ? Yb : Xb) + rowbase + (long)rr * N + cc2;
            stg[it] = *(const f2*)src;
        }
#pragma unroll
        for (int it = 0; it < 13; it++) {
            int idx2 = tid + 256 * it;
            int img2 = idx2 >= 1664;
            int rem = idx2 - img2 * 1664;
            int rr = rem >> 6;
            int cc2 = (rem & 63) * 2;
            *(f2*)&smem[img2 * 3328 + rr * 128 + cc2] = stg[it];
        }
        __syncthreads();
        // ---- column gather from LDS (lane stride 4B -> 2-way = free) ------
#pragma unroll
        for (int i = 0; i < 18; i++) {
            int rr = 8 * s + i;
            xy[i].x = smem[rr * 128 + c];
            xy[i].y = smem[3328 + rr * 128 + c];
        }
        __syncthreads();   // raw region is overwritten by planes below
    } else {
        const int cic = min(ci, N - 1);
#pragma unroll
        for (int i = 0; i < 18; i++) {
            int rc = min(oy0 + 8 * s + i, N - 1);
            xy[i].x = Xb[(long)rc * N + cic];
            xy[i].y = Yb[(long)rc * N + cic];
        }
        __builtin_amdgcn_sched_barrier(0);
    }

    if (SIG) {
#pragma unroll
        for (int i = 0; i < 18; i++) xy[i].x = fsig(xy[i].x);
    }

    // ================= phase 1b: vertical filter (packed) ===================
    f2 a01[8], a23[8];
    float ayy[SKIPYY ? 1 : 8];
#pragma unroll
    for (int o = 0; o < 8; o++) {
        a01[o] = (f2){0.f, 0.f};
        a23[o] = (f2){0.f, 0.f};
        if constexpr (!SKIPYY) ayy[o] = 0.f;
    }

#pragma unroll
    for (int i = 0; i < 18; i++) {
        f2 v01 = xy[i];
        f2 xb = (f2){v01.x, v01.x};
        f2 v23 = xb * v01;                       // {x*x, x*y} packed mul
        float yy;
        if constexpr (!SKIPYY) yy = v01.y * v01.y;
#pragma unroll
        for (int o = 0; o < 8; o++) {
            int t = i - o;
            if (t >= 0 && t < 11) {              // folds statically after unroll
                f2 w = (f2){W[t], W[t]};
                a01[o] = pkfma(w, v01, a01[o]);
                a23[o] = pkfma(w, v23, a23[o]);
                if constexpr (!SKIPYY) ayy[o] = fmaf(W[t], yy, ayy[o]);
            }
        }
    }

    // ================= phase 1c: fused 2x2 pool (batched shuffles) ==========
    if (POOL) {
        float cx[4], cy[4];
#pragma unroll
        for (int p = 0; p < 4; p++) {
            cx[p] = xy[2 * p].x + xy[2 * p + 1].x;
            cy[p] = xy[2 * p].y + xy[2 * p + 1].y;
        }
#pragma unroll
        for (int p = 0; p < 4; p++) {
            float rx = __shfl_down(cx[p], 1, 64);   // column c+1 (same wave)
            float ry = __shfl_down(cy[p], 1, 64);
            if (!(c & 1) && c < powned) {
                int orow = (oy0 + 8 * s + 2 * p) >> 1;
                int ocol = ci >> 1;
                long pb = (long)img * half * half + (long)orow * half + ocol;
                poolX[pb] = 0.25f * (cx[p] + rx);
                poolY[pb] = 0.25f * (cy[p] + ry);
            }
        }
    }

    // ---- LDS write: float4 column {mu1,mu2,xx,xy} at XOR-swizzled position
    // main plane floats [0,8192); yy scalar plane [8192,10240)
#pragma unroll
    for (int o = 0; o < 8; o++) {
        int rr = 8 * s + o;
        int phys = c ^ (((c >> 3) + rr) & 7);           // bijective per row
        float4 v;
        v.x = a01[o].x; v.y = a01[o].y; v.z = a23[o].x; v.w = a23[o].y;
        *(float4*)&smem[rr * 512 + phys * 4] = v;
        if constexpr (!SKIPYY) {
            int ch = c >> 2;
            int pc = ch ^ (((ch >> 3) + rr) & 7);       // f4-chunk swizzle
            smem[8192 + rr * 128 + pc * 4 + (c & 3)] = ayy[o];
        }
    }
    __syncthreads();

    // ================= phase 2: horizontal filter + SSIM ====================
    const float C1 = 1e-4f, C2 = 9e-4f;
    float scs = 0.f, sss = 0.f;
    {
        const int r = tid >> 4;    // output row within tile
        const int k = tid & 15;    // 8-px column segment
        if (k < 15) {              // segment base 8k must be < 118
            f2 a01h[8], a23h[8];
#pragma unroll
            for (int j = 0; j < 8; j++) {
                a01h[j] = (f2){0.f, 0.f};
                a23h[j] = (f2){0.f, 0.f};
            }
            // accumulate-on-load: one f4 read delivers all 4 quantities of a
            // column; rg value is dead after its 8 (j,t) uses -> low liveness
#pragma unroll
            for (int m = 0; m < 18; m++) {
                int col = 8 * k + m;                    // may be 128/129 @k=14
                int g = (k + (m >> 3) + r) & 7;         // == ((col>>3)+r)&7
                int phys = (col ^ g) & 127;             // wrap: garbage masked
                const float4 v4 = *(const float4*)&smem[r * 512 + phys * 4];
                f2 v01 = (f2){v4.x, v4.y};
                f2 v23 = (f2){v4.z, v4.w};
#pragma unroll
                for (int j = 0; j < 8; j++) {
                    int t = m - j;
                    if (t >= 0 && t < 11) {             // folds statically
                        f2 w = (f2){W[t], W[t]};
                        a01h[j] = pkfma(w, v01, a01h[j]);
                        a23h[j] = pkfma(w, v23, a23h[j]);
                    }
                }
            }
            // ---- scalar yy plane (non-SKIPYY only) ------------------------
            float oyy[8];
            if constexpr (!SKIPYY) {
                float rgs[20];
#pragma unroll
                for (int j5 = 0; j5 < 5; j5++) {
                    int ch = 2 * k + j5;                // may be 32 @k=14
                    int pc = (ch ^ (((ch >> 3) + r) & 7)) & 31;
                    const float4 v4 = *(const float4*)&smem[8192 + r * 128 + pc * 4];
                    rgs[4 * j5 + 0] = v4.x; rgs[4 * j5 + 1] = v4.y;
                    rgs[4 * j5 + 2] = v4.z; rgs[4 * j5 + 3] = v4.w;
                }
#pragma unroll
                for (int j = 0; j < 8; j++) {
                    float a = 0.f;
#pragma unroll
                    for (int t = 0; t < 11; t++) a = fmaf(W[t], rgs[j + t], a);
                    oyy[j] = a;
                }
            }
            const int gy = oy0 + r;
            const bool rowok = gy < M;          // uniform per thread, hoisted
#pragma unroll
            for (int j = 0; j < 8; j++) {
                int lc = 8 * k + j;
                int gx = ox0 + lc;
                if (lc < TW && gx < M && rowok) {
                    float mu1 = a01h[j].x, mu2 = a01h[j].y;
                    float exx = a23h[j].x, exy = a23h[j].y;
                    float m11 = mu1 * mu1, m22 = mu2 * mu2, m12 = mu1 * mu2;
                    float s1 = exx - m11;
                    float s2 = SKIPYY ? (mu2 - m22) : (oyy[j] - m22);
                    float s12 = exy - m12;
                    float cs = (2.f * s12 + C2) * frcp(s1 + s2 + C2);
                    float ssim = (2.f * m12 + C1) * frcp(m11 + m22 + C1) * cs;
                    scs += cs; sss += ssim;
                }
            }
        }
    }

    // block reduction (reuse smem after barrier)
    for (int off = 32; off > 0; off >>= 1) {
        scs += __shfl_down(scs, off, 64);
        sss += __shfl_down(sss, off, 64);
    }
    __syncthreads();
    int lane = tid & 63, wv = tid >> 6;
    if (lane == 0) { smem[wv] = scs; smem[4 + wv] = sss; }
    __syncthreads();
    if (tid == 0) {
        atomicAdd(&accCs[img],   smem[0] + smem[1] + smem[2] + smem[3]);
        atomicAdd(&accSsim[img], smem[4] + smem[5] + smem[6] + smem[7]);
    }
}

// ---------------------------------------------------------------------------
// Grid kernels (proven 5-launch structure).
// ---------------------------------------------------------------------------
template <int N, int M, bool SIG, bool POOL, bool SKIPYY, bool NARROW>
__global__ __launch_bounds__(256, 4)
void ssim_kernel(const float* __restrict__ X, const float* __restrict__ Y,
                 float* __restrict__ accSsim, float* __restrict__ accCs,
                 float* __restrict__ poolX, float* __restrict__ poolY) {
    __shared__ float smem[10240];              // 40960 B -> 4 blocks/CU
    ssim_tile<N, M, SIG, POOL, SKIPYY, NARROW>(X, Y, accSsim, accCs, poolX, poolY,
                                               blockIdx.z, blockIdx.x, blockIdx.y, smem);
}

// acc layout: level l -> [l*2*NIMG .. +NIMG) ssim sums, [+NIMG .. +2*NIMG) cs sums
__global__ __launch_bounds__(128)
void finalize_kernel(const float* __restrict__ acc, float* __restrict__ out) {
    const float wts[5] = {0.0448f, 0.2856f, 0.3001f, 0.2363f, 0.1333f};
    const int Ms[5] = {502, 246, 118, 54, 22};
    int t = threadIdx.x;
    float v = 0.f;
    if (t < NIMG) {
        float prod = 1.f;
#pragma unroll
        for (int l = 0; l < 5; l++) {
            float inv = 1.0f / ((float)Ms[l] * (float)Ms[l]);
            float m = (l < 4) ? acc[l * 2 * NIMG + NIMG + t] * inv   // cs mean
                              : acc[l * 2 * NIMG + t] * inv;          // ssim mean
            m = fmaxf(m, 0.f);                                        // relu
            prod *= powf(m, wts[l]);
        }
        v = prod;
    }
    for (int off = 32; off > 0; off >>= 1) v += __shfl_down(v, off, 64);
    __shared__ float red[2];
    if ((t & 63) == 0) red[t >> 6] = v;
    __syncthreads();
    if (t == 0) out[0] = 1.0f - (red[0] + red[1]) / (float)NIMG;
}

extern "C" void kernel_launch(void* const* d_in, const int* in_sizes, int n_in,
                              void* d_out, int out_size, void* d_ws, size_t ws_size,
                              hipStream_t stream) {
    const float* logits = (const float*)d_in[0];
    const float* targets = (const float*)d_in[1];
    float* out = (float*)d_out;
    float* ws = (float*)d_ws;

    // workspace layout (floats)
    float* acc = ws;                               // 5*2*116 = 1160 floats
    size_t off = 1280;
    float* X1 = ws + off; off += (size_t)NIMG * 256 * 256;
    float* Y1 = ws + off; off += (size_t)NIMG * 256 * 256;
    float* X2 = ws + off; off += (size_t)NIMG * 128 * 128;
    float* Y2 = ws + off; off += (size_t)NIMG * 128 * 128;
    float* X3 = ws + off; off += (size_t)NIMG * 64 * 64;
    float* Y3 = ws + off; off += (size_t)NIMG * 64 * 64;
    float* X4 = ws + off; off += (size_t)NIMG * 32 * 32;
    float* Y4 = ws + off; off += (size_t)NIMG * 32 * 32;

    hipMemsetAsync(acc, 0, 1160 * sizeof(float), stream);

    // level 0: sigmoid + pool fused, binary targets -> SKIPYY
    {
        dim3 grid((512 + TW - 1) / TW, 512 / TH, NIMG);
        ssim_kernel<512, 502, true, true, true, false><<<grid, 256, 0, stream>>>(
            logits, targets, acc, acc + NIMG, X1, Y1);
    }
    // level 1: N=256, wide tiles
    {
        dim3 grid((256 + TW - 1) / TW, 256 / TH, NIMG);
        ssim_kernel<256, 246, false, true, false, false><<<grid, 256, 0, stream>>>(
            X1, Y1, acc + 2 * NIMG, acc + 3 * NIMG, X2, Y2);
    }
    // level 2: N=128, single x-tile
    {
        dim3 grid(1, 128 / TH, NIMG);
        ssim_kernel<128, 118, false, true, false, true><<<grid, 256, 0, stream>>>(
            X2, Y2, acc + 4 * NIMG, acc + 5 * NIMG, X3, Y3);
    }
    // level 3: N=64, single x-tile
    {
        dim3 grid(1, 64 / TH, NIMG);
        ssim_kernel<64, 54, false, true, false, true><<<grid, 256, 0, stream>>>(
            X3, Y3, acc + 6 * NIMG, acc + 7 * NIMG, X4, Y4);
    }
    // level 4: N=32, single x-tile, no pool
    {
        dim3 grid(1, 32 / TH, NIMG);
        ssim_kernel<32, 22, false, false, false, true><<<grid, 256, 0, stream>>>(
            X4, Y4, acc + 8 * NIMG, acc + 9 * NIMG, nullptr, nullptr);
    }

    finalize_kernel<<<1, 128, 0, stream>>>(acc, out);
}

// Round 8
// 415.956 us; speedup vs baseline: 1.0153x; 1.0153x over previous
//
#include <hip/hip_runtime.h>
#include <math.h>

#define NIMG 116          // 4*29 images
#define TW 118            // output tile width  (phase-1 columns = TW+10 = 128)
#define TH 16             // output tile height (strips of 8 rows, 2 strips)

// 11-tap Gaussian (size=11, sigma=1.5), fp32 values matching the reference.
static constexpr float W[11] = {
    0.00102838f, 0.00759876f, 0.03600078f, 0.10936075f, 0.21300554f,
    0.26601172f, 0.21300554f, 0.10936075f, 0.03600078f, 0.00759876f,
    0.00102838f};

typedef float f2 __attribute__((ext_vector_type(2)));

__device__ __forceinline__ f2 pkfma(f2 a, f2 b, f2 c) {
#if __has_builtin(__builtin_elementwise_fma)
    return __builtin_elementwise_fma(a, b, c);
#else
    f2 r; r.x = fmaf(a.x, b.x, c.x); r.y = fmaf(a.y, b.y, c.y); return r;
#endif
}

__device__ __forceinline__ float frcp(float x) {
    return __builtin_amdgcn_rcpf(x);
}

__device__ __forceinline__ float fsig(float x) {
    float e = __builtin_amdgcn_exp2f(x * -1.4426950408889634f);
    return frcp(1.0f + e);
}

// ---------------------------------------------------------------------------
// Per-tile SSIM body, packed-FP32 + bank-swizzled LDS (R6 structure).
// R5: pkfma cut VALU issue 80->58% busy but f2-interleaved LDS raised
//     conflicts 8M->20M — net zero.
// R6: float4-column {mu1,mu2,xx,xy} plane + XOR swizzle -> conflicts 0,
//     L0 193->181 µs, total 414.5 (best).
// R7: LDS-staged phase-1 loads REGRESSED (181->191): strided loads are
//     L2-absorbed, not latency-critical; staging = pure instruction overhead.
//     Reverted here. Phase-1 loads are exonerated as a bottleneck.
// R8: hoist the 11 packed weight-pairs WP[] into pinned VGPRs (single
//     keep-alive). Theory: VOP3P has no 64-bit literal form, so un-hoisted
//     {W,W} operands re-materialize as v_mov pairs per pkfma (~700/thread,
//     2x the FMA count) — the unexplained ~50 µs VALU residue at L0.
// LDS: planes 8192 f + yy 2048 f = 40960 B -> exactly 4 blocks/CU
// (R4: 32 KB/5 blocks raised HBM traffic 12%; locality beats occupancy).
// History: R1 keep-alive-on-loads -5 µs reverted; R2 grid.sync raced;
// R4 tail serialization +35 µs reverted. Structure = proven 5 + finalize.
// ---------------------------------------------------------------------------
template <int N, int M, bool SIG, bool POOL, bool SKIPYY, bool NARROW>
__device__ __forceinline__ void ssim_tile(
    const float* __restrict__ X, const float* __restrict__ Y,
    float* __restrict__ accSsim, float* __restrict__ accCs,
    float* __restrict__ poolX, float* __restrict__ poolY,
    int img, int bx, int by, float* smem) {
    const int tid = threadIdx.x;
    const int ox0 = NARROW ? 0 : bx * TW;
    const int oy0 = by * TH;
    const long base = (long)img * N * N;

    // ================= phase 1: batch load ==================================
    const int c  = tid & 127;      // tile-local column 0..127
    const int s  = tid >> 7;       // strip 0/1 (rows 8s .. 8s+7 of v)
    const int ci = ox0 + c;        // global column
    constexpr int half = N >> 1;
    const int powned = NARROW ? N : min(TW, N - ox0);  // pool column ownership

    const float* __restrict__ Xb = X + base;
    const float* __restrict__ Yb = Y + base;

    // interior: no row/col clamping anywhere in this block (block-uniform)
    const bool interior = (oy0 + 25 < N) && (ox0 + 127 < N);

    f2 xy[18];                     // .x = X row value, .y = Y row value
    if (interior) {
        const float* __restrict__ xp = Xb + (long)(oy0 + 8 * s) * N + ci;
        const float* __restrict__ yp = Yb + (long)(oy0 + 8 * s) * N + ci;
#pragma unroll
        for (int i = 0; i < 18; i++) {
            xy[i].x = xp[(long)i * N];
            xy[i].y = yp[(long)i * N];
        }
    } else {
        const int cic = min(ci, N - 1);
#pragma unroll
        for (int i = 0; i < 18; i++) {
            int rc = min(oy0 + 8 * s + i, N - 1);
            xy[i].x = Xb[(long)rc * N + cic];
            xy[i].y = Yb[(long)rc * N + cic];
        }
    }
    __builtin_amdgcn_sched_barrier(0);

    if (SIG) {
#pragma unroll
        for (int i = 0; i < 18; i++) xy[i].x = fsig(xy[i].x);
    }

    // ---- hoisted packed weight pairs: pin {W,W} in VGPRs once, so VOP3P
    // pkfma sources a register instead of re-materializing a 64-bit pair
    // per use (VOP3P has no 64-bit literal). 22 VGPRs; budget is 128.
    f2 WP[11];
#pragma unroll
    for (int t = 0; t < 11; t++) WP[t] = (f2){W[t], W[t]};
    asm volatile("" ::
        "v"(WP[0]), "v"(WP[1]), "v"(WP[2]), "v"(WP[3]), "v"(WP[4]),
        "v"(WP[5]), "v"(WP[6]), "v"(WP[7]), "v"(WP[8]), "v"(WP[9]),
        "v"(WP[10]));

    // ================= phase 1b: vertical filter (packed) ===================
    f2 a01[8], a23[8];
    float ayy[SKIPYY ? 1 : 8];
#pragma unroll
    for (int o = 0; o < 8; o++) {
        a01[o] = (f2){0.f, 0.f};
        a23[o] = (f2){0.f, 0.f};
        if constexpr (!SKIPYY) ayy[o] = 0.f;
    }

#pragma unroll
    for (int i = 0; i < 18; i++) {
        f2 v01 = xy[i];
        f2 xb = (f2){v01.x, v01.x};
        f2 v23 = xb * v01;                       // {x*x, x*y} packed mul
        float yy;
        if constexpr (!SKIPYY) yy = v01.y * v01.y;
#pragma unroll
        for (int o = 0; o < 8; o++) {
            int t = i - o;
            if (t >= 0 && t < 11) {              // folds statically after unroll
                a01[o] = pkfma(WP[t], v01, a01[o]);
                a23[o] = pkfma(WP[t], v23, a23[o]);
                if constexpr (!SKIPYY) ayy[o] = fmaf(W[t], yy, ayy[o]);
            }
        }
    }

    // ================= phase 1c: fused 2x2 pool (batched shuffles) ==========
    if (POOL) {
        float cx[4], cy[4];
#pragma unroll
        for (int p = 0; p < 4; p++) {
            cx[p] = xy[2 * p].x + xy[2 * p + 1].x;
            cy[p] = xy[2 * p].y + xy[2 * p + 1].y;
        }
#pragma unroll
        for (int p = 0; p < 4; p++) {
            float rx = __shfl_down(cx[p], 1, 64);   // column c+1 (same wave)
            float ry = __shfl_down(cy[p], 1, 64);
            if (!(c & 1) && c < powned) {
                int orow = (oy0 + 8 * s + 2 * p) >> 1;
                int ocol = ci >> 1;
                long pb = (long)img * half * half + (long)orow * half + ocol;
                poolX[pb] = 0.25f * (cx[p] + rx);
                poolY[pb] = 0.25f * (cy[p] + ry);
            }
        }
    }

    // ---- LDS write: float4 column {mu1,mu2,xx,xy} at XOR-swizzled position
    // main plane floats [0,8192); yy scalar plane [8192,10240)
#pragma unroll
    for (int o = 0; o < 8; o++) {
        int rr = 8 * s + o;
        int phys = c ^ (((c >> 3) + rr) & 7);           // bijective per row
        float4 v;
        v.x = a01[o].x; v.y = a01[o].y; v.z = a23[o].x; v.w = a23[o].y;
        *(float4*)&smem[rr * 512 + phys * 4] = v;
        if constexpr (!SKIPYY) {
            int ch = c >> 2;
            int pc = ch ^ (((ch >> 3) + rr) & 7);       // f4-chunk swizzle
            smem[8192 + rr * 128 + pc * 4 + (c & 3)] = ayy[o];
        }
    }
    __syncthreads();

    // ================= phase 2: horizontal filter + SSIM ====================
    const float C1 = 1e-4f, C2 = 9e-4f;
    float scs = 0.f, sss = 0.f;
    {
        const int r = tid >> 4;    // output row within tile
        const int k = tid & 15;    // 8-px column segment
        if (k < 15) {              // segment base 8k must be < 118
            f2 a01h[8], a23h[8];
#pragma unroll
            for (int j = 0; j < 8; j++) {
                a01h[j] = (f2){0.f, 0.f};
                a23h[j] = (f2){0.f, 0.f};
            }
            // accumulate-on-load: one f4 read delivers all 4 quantities of a
            // column; rg value is dead after its 8 (j,t) uses -> low liveness
#pragma unroll
            for (int m = 0; m < 18; m++) {
                int col = 8 * k + m;                    // may be 128/129 @k=14
                int g = (k + (m >> 3) + r) & 7;         // == ((col>>3)+r)&7
                int phys = (col ^ g) & 127;             // wrap: garbage masked
                const float4 v4 = *(const float4*)&smem[r * 512 + phys * 4];
                f2 v01 = (f2){v4.x, v4.y};
                f2 v23 = (f2){v4.z, v4.w};
#pragma unroll
                for (int j = 0; j < 8; j++) {
                    int t = m - j;
                    if (t >= 0 && t < 11) {             // folds statically
                        a01h[j] = pkfma(WP[t], v01, a01h[j]);
                        a23h[j] = pkfma(WP[t], v23, a23h[j]);
                    }
                }
            }
            // ---- scalar yy plane (non-SKIPYY only) ------------------------
            float oyy[8];
            if constexpr (!SKIPYY) {
                float rgs[20];
#pragma unroll
                for (int j5 = 0; j5 < 5; j5++) {
                    int ch = 2 * k + j5;                // may be 32 @k=14
                    int pc = (ch ^ (((ch >> 3) + r) & 7)) & 31;
                    const float4 v4 = *(const float4*)&smem[8192 + r * 128 + pc * 4];
                    rgs[4 * j5 + 0] = v4.x; rgs[4 * j5 + 1] = v4.y;
                    rgs[4 * j5 + 2] = v4.z; rgs[4 * j5 + 3] = v4.w;
                }
#pragma unroll
                for (int j = 0; j < 8; j++) {
                    float a = 0.f;
#pragma unroll
                    for (int t = 0; t < 11; t++) a = fmaf(W[t], rgs[j + t], a);
                    oyy[j] = a;
                }
            }
            const int gy = oy0 + r;
            const bool rowok = gy < M;          // uniform per thread, hoisted
#pragma unroll
            for (int j = 0; j < 8; j++) {
                int lc = 8 * k + j;
                int gx = ox0 + lc;
                if (lc < TW && gx < M && rowok) {
                    float mu1 = a01h[j].x, mu2 = a01h[j].y;
                    float exx = a23h[j].x, exy = a23h[j].y;
                    float m11 = mu1 * mu1, m22 = mu2 * mu2, m12 = mu1 * mu2;
                    float s1 = exx - m11;
                    float s2 = SKIPYY ? (mu2 - m22) : (oyy[j] - m22);
                    float s12 = exy - m12;
                    float cs = (2.f * s12 + C2) * frcp(s1 + s2 + C2);
                    float ssim = (2.f * m12 + C1) * frcp(m11 + m22 + C1) * cs;
                    scs += cs; sss += ssim;
                }
            }
        }
    }

    // block reduction (reuse smem after barrier)
    for (int off = 32; off > 0; off >>= 1) {
        scs += __shfl_down(scs, off, 64);
        sss += __shfl_down(sss, off, 64);
    }
    __syncthreads();
    int lane = tid & 63, wv = tid >> 6;
    if (lane == 0) { smem[wv] = scs; smem[4 + wv] = sss; }
    __syncthreads();
    if (tid == 0) {
        atomicAdd(&accCs[img],   smem[0] + smem[1] + smem[2] + smem[3]);
        atomicAdd(&accSsim[img], smem[4] + smem[5] + smem[6] + smem[7]);
    }
}

// ---------------------------------------------------------------------------
// Grid kernels (proven 5-launch structure).
// ---------------------------------------------------------------------------
template <int N, int M, bool SIG, bool POOL, bool SKIPYY, bool NARROW>
__global__ __launch_bounds__(256, 4)
void ssim_kernel(const float* __restrict__ X, const float* __restrict__ Y,
                 float* __restrict__ accSsim, float* __restrict__ accCs,
                 float* __restrict__ poolX, float* __restrict__ poolY) {
    __shared__ float smem[10240];              // 40960 B -> 4 blocks/CU
    ssim_tile<N, M, SIG, POOL, SKIPYY, NARROW>(X, Y, accSsim, accCs, poolX, poolY,
                                               blockIdx.z, blockIdx.x, blockIdx.y, smem);
}

// acc layout: level l -> [l*2*NIMG .. +NIMG) ssim sums, [+NIMG .. +2*NIMG) cs sums
__global__ __launch_bounds__(128)
void finalize_kernel(const float* __restrict__ acc, float* __restrict__ out) {
    const float wts[5] = {0.0448f, 0.2856f, 0.3001f, 0.2363f, 0.1333f};
    const int Ms[5] = {502, 246, 118, 54, 22};
    int t = threadIdx.x;
    float v = 0.f;
    if (t < NIMG) {
        float prod = 1.f;
#pragma unroll
        for (int l = 0; l < 5; l++) {
            float inv = 1.0f / ((float)Ms[l] * (float)Ms[l]);
            float m = (l < 4) ? acc[l * 2 * NIMG + NIMG + t] * inv   // cs mean
                              : acc[l * 2 * NIMG + t] * inv;          // ssim mean
            m = fmaxf(m, 0.f);                                        // relu
            prod *= powf(m, wts[l]);
        }
        v = prod;
    }
    for (int off = 32; off > 0; off >>= 1) v += __shfl_down(v, off, 64);
    __shared__ float red[2];
    if ((t & 63) == 0) red[t >> 6] = v;
    __syncthreads();
    if (t == 0) out[0] = 1.0f - (red[0] + red[1]) / (float)NIMG;
}

extern "C" void kernel_launch(void* const* d_in, const int* in_sizes, int n_in,
                              void* d_out, int out_size, void* d_ws, size_t ws_size,
                              hipStream_t stream) {
    const float* logits = (const float*)d_in[0];
    const float* targets = (const float*)d_in[1];
    float* out = (float*)d_out;
    float* ws = (float*)d_ws;

    // workspace layout (floats)
    float* acc = ws;                               // 5*2*116 = 1160 floats
    size_t off = 1280;
    float* X1 = ws + off; off += (size_t)NIMG * 256 * 256;
    float* Y1 = ws + off; off += (size_t)NIMG * 256 * 256;
    float* X2 = ws + off; off += (size_t)NIMG * 128 * 128;
    float* Y2 = ws + off; off += (size_t)NIMG * 128 * 128;
    float* X3 = ws + off; off += (size_t)NIMG * 64 * 64;
    float* Y3 = ws + off; off += (size_t)NIMG * 64 * 64;
    float* X4 = ws + off; off += (size_t)NIMG * 32 * 32;
    float* Y4 = ws + off; off += (size_t)NIMG * 32 * 32;

    hipMemsetAsync(acc, 0, 1160 * sizeof(float), stream);

    // level 0: sigmoid + pool fused, binary targets -> SKIPYY
    {
        dim3 grid((512 + TW - 1) / TW, 512 / TH, NIMG);
        ssim_kernel<512, 502, true, true, true, false><<<grid, 256, 0, stream>>>(
            logits, targets, acc, acc + NIMG, X1, Y1);
    }
    // level 1: N=256, wide tiles
    {
        dim3 grid((256 + TW - 1) / TW, 256 / TH, NIMG);
        ssim_kernel<256, 246, false, true, false, false><<<grid, 256, 0, stream>>>(
            X1, Y1, acc + 2 * NIMG, acc + 3 * NIMG, X2, Y2);
    }
    // level 2: N=128, single x-tile
    {
        dim3 grid(1, 128 / TH, NIMG);
        ssim_kernel<128, 118, false, true, false, true><<<grid, 256, 0, stream>>>(
            X2, Y2, acc + 4 * NIMG, acc + 5 * NIMG, X3, Y3);
    }
    // level 3: N=64, single x-tile
    {
        dim3 grid(1, 64 / TH, NIMG);
        ssim_kernel<64, 54, false, true, false, true><<<grid, 256, 0, stream>>>(
            X3, Y3, acc + 6 * NIMG, acc + 7 * NIMG, X4, Y4);
    }
    // level 4: N=32, single x-tile, no pool
    {
        dim3 grid(1, 32 / TH, NIMG);
        ssim_kernel<32, 22, false, false, false, true><<<grid, 256, 0, stream>>>(
            X4, Y4, acc + 8 * NIMG, acc + 9 * NIMG, nullptr, nullptr);
    }

    finalize_kernel<<<1, 128, 0, stream>>>(acc, out);
}